// Round 1
// baseline (287.657 us; speedup 1.0000x reference)
//
#include <hip/hip_runtime.h>

// SmallRNN: B=4096 chains, T=2048 steps, I=1, H=8, O=1, fp32.
// h_t = tanh(x_t*w_ih + W_hh h_{t-1} + b);  out = fc_w . h_T + fc_b
//
// Decomposition: 16 lanes per chain (8 hidden units x 2 replicas to fill a
// 16-lane DPP row for later rounds). 256 threads/block = 16 chains/block,
// grid 256 -> 1024 waves = 1 wave per SIMD across all 256 CUs.
// Cross-lane h exchange via __shfl (ds_bpermute, wave-internal, no barrier).

#define B_TOTAL 4096
#define T_STEPS 2048
#define H 8

__device__ __forceinline__ float fast_tanh(float s) {
    // tanh(s) = 1 - 2/(1 + exp(2s));  exp(2s) = exp2(s * 2*log2(e))
    // v_exp_f32 / v_rcp_f32: ~1 ulp, handles +-inf saturation correctly.
    float e = __builtin_amdgcn_exp2f(s * 2.885390081777927f);
    return 1.0f - 2.0f * __builtin_amdgcn_rcpf(1.0f + e);
}

__global__ __launch_bounds__(256, 1) void rnn_fused(
    const float* __restrict__ x,      // [4096, 2048]
    const float* __restrict__ w_ih,   // [8,1]
    const float* __restrict__ w_hh,   // [8,8]
    const float* __restrict__ b_ih,   // [8]
    const float* __restrict__ b_hh,   // [8]
    const float* __restrict__ fc_w,   // [1,8]
    const float* __restrict__ fc_b,   // [1]
    float* __restrict__ out)          // [4096,1]
{
    const int tid      = threadIdx.x;
    const int p        = tid & 15;          // position within 16-lane row
    const int j        = p & 7;             // hidden index (replica-agnostic)
    const int chain    = (blockIdx.x << 4) + (tid >> 4);
    const int baseLane = tid & 48;          // wave-relative base of this row

    // Per-lane weights: row j of W_hh, plus input weight and fused bias.
    float w[H];
#pragma unroll
    for (int k = 0; k < H; ++k) w[k] = w_hh[j * H + k];
    const float wih = w_ih[j];
    const float bj  = b_ih[j] + b_hh[j];

    const float* xp = x + (size_t)chain * T_STEPS;

    float h = 0.0f;

    // One RNN step. Two parallel fma chains shorten the dependency path.
#define STEP(xval)                                         \
    {                                                      \
        float g0 = __shfl(h, baseLane + 0);                \
        float g1 = __shfl(h, baseLane + 1);                \
        float g2 = __shfl(h, baseLane + 2);                \
        float g3 = __shfl(h, baseLane + 3);                \
        float g4 = __shfl(h, baseLane + 4);                \
        float g5 = __shfl(h, baseLane + 5);                \
        float g6 = __shfl(h, baseLane + 6);                \
        float g7 = __shfl(h, baseLane + 7);                \
        float sa = fmaf((xval), wih, bj);                  \
        float sb = w[4] * g4;                              \
        sa = fmaf(w[0], g0, sa);                           \
        sb = fmaf(w[5], g5, sb);                           \
        sa = fmaf(w[1], g1, sa);                           \
        sb = fmaf(w[6], g6, sb);                           \
        sa = fmaf(w[2], g2, sa);                           \
        sb = fmaf(w[7], g7, sb);                           \
        sa = fmaf(w[3], g3, sa);                           \
        h  = fast_tanh(sa + sb);                           \
    }

    // Unroll 16 steps per iteration; prefetch the next 16 x-values one full
    // group (~1.7k cycles) ahead so the x stream never stalls the recurrence.
    float4 c0 = *(const float4*)(xp + 0);
    float4 c1 = *(const float4*)(xp + 4);
    float4 c2 = *(const float4*)(xp + 8);
    float4 c3 = *(const float4*)(xp + 12);

    for (int t = 0; t < T_STEPS; t += 16) {
        float4 n0 = c0, n1 = c1, n2 = c2, n3 = c3;
        if (t + 16 < T_STEPS) {
            n0 = *(const float4*)(xp + t + 16);
            n1 = *(const float4*)(xp + t + 20);
            n2 = *(const float4*)(xp + t + 24);
            n3 = *(const float4*)(xp + t + 28);
        }
        STEP(c0.x) STEP(c0.y) STEP(c0.z) STEP(c0.w)
        STEP(c1.x) STEP(c1.y) STEP(c1.z) STEP(c1.w)
        STEP(c2.x) STEP(c2.y) STEP(c2.z) STEP(c2.w)
        STEP(c3.x) STEP(c3.y) STEP(c3.z) STEP(c3.w)
        c0 = n0; c1 = n1; c2 = n2; c3 = n3;
    }
#undef STEP

    // Final FC: gather h_T once more; lane p==0 of each chain writes output.
    float g[H];
#pragma unroll
    for (int k = 0; k < H; ++k) g[k] = __shfl(h, baseLane + k);
    if (p == 0) {
        float o = fc_b[0];
#pragma unroll
        for (int k = 0; k < H; ++k) o = fmaf(fc_w[k], g[k], o);
        out[chain] = o;
    }
}

extern "C" void kernel_launch(void* const* d_in, const int* in_sizes, int n_in,
                              void* d_out, int out_size, void* d_ws, size_t ws_size,
                              hipStream_t stream) {
    const float* x    = (const float*)d_in[0];
    const float* w_ih = (const float*)d_in[1];
    const float* w_hh = (const float*)d_in[2];
    const float* b_ih = (const float*)d_in[3];
    const float* b_hh = (const float*)d_in[4];
    const float* fc_w = (const float*)d_in[5];
    const float* fc_b = (const float*)d_in[6];
    float* out = (float*)d_out;

    dim3 grid(B_TOTAL / 16);   // 256 blocks -> 1 per CU
    dim3 block(256);           // 4 waves -> 1 per SIMD
    hipLaunchKernelGGL(rnn_fused, grid, block, 0, stream,
                       x, w_ih, w_hh, b_ih, b_hh, fc_w, fc_b, out);
}

// Round 2
// 175.783 us; speedup vs baseline: 1.6364x; 1.6364x over previous
//
#include <hip/hip_runtime.h>

// SmallRNN: B=4096 chains, T=2048 steps, I=1, H=8, O=1, fp32.
// h_t = tanh(x_t*w_ih + W_hh h_{t-1} + b);  out = fc_w . h_T + fc_b
//
// Round 2: cross-lane h exchange via DPP (full-rate VALU, ~4cy latency)
// instead of __shfl/ds_bpermute (~120cy LDS round-trip on the critical path).
// Only self-inverse XOR patterns are used so lane mapping is unambiguous:
//   quad_perm 0xB1 = XOR1, 0x4E = XOR2, 0x1B = XOR3 (intra-quad)
//   row_half_mirror 0x141 = XOR7 (within 8 lanes)
//   XOR4/5/6 = half_mirror composed with quad_perm.
// Lane j receives h[j^N] and multiplies by precomputed w_hh[j][j^N].
// Weights/bias pre-scaled by 2*log2(e) so tanh needs no mul before exp2.
//
// Layout: 16 lanes per chain (8 hidden units x 2 replicas; all DPP exchange
// is within 8-lane halves so replicas are independent). 256 thr/block =
// 16 chains/block, grid 256 -> 1024 waves = 1 wave/SIMD on all 256 CUs.

#define B_TOTAL 4096
#define T_STEPS 2048
#define H 8

template <int CTRL>
__device__ __forceinline__ float dppf(float v) {
    int i = __float_as_int(v);
    i = __builtin_amdgcn_mov_dpp(i, CTRL, 0xF, 0xF, true);
    return __int_as_float(i);
}

__global__ __launch_bounds__(256, 1) void rnn_fused(
    const float* __restrict__ x,      // [4096, 2048]
    const float* __restrict__ w_ih,   // [8,1]
    const float* __restrict__ w_hh,   // [8,8]
    const float* __restrict__ b_ih,   // [8]
    const float* __restrict__ b_hh,   // [8]
    const float* __restrict__ fc_w,   // [1,8]
    const float* __restrict__ fc_b,   // [1]
    float* __restrict__ out)          // [4096,1]
{
    const int tid      = threadIdx.x;
    const int p        = tid & 15;          // position within 16-lane row
    const int j        = p & 7;             // hidden index (replica-agnostic)
    const int chain    = (blockIdx.x << 4) + (tid >> 4);
    const int baseLane = tid & 48;          // wave-relative base of this row

    // 2*log2(e): folds the exp(2s) = exp2(C*s) scale into weights & bias.
    const float C = 2.885390081777927f;

    // Per-lane weights: wx[N] multiplies the value arriving via XOR-N,
    // which is h[j^N]  ->  wx[N] = w_hh[j][j^N], pre-scaled by C.
    float wx[H];
#pragma unroll
    for (int N = 0; N < H; ++N) wx[N] = w_hh[j * H + (j ^ N)] * C;
    const float wihC = w_ih[j] * C;
    const float bjC  = (b_ih[j] + b_hh[j]) * C;

    const float* xp = x + (size_t)chain * T_STEPS;

    float h = 0.0f;

    // One RNN step. 3 parallel fma chains; DPP moves are 2 dependency levels.
#define STEP(xval)                                         \
    {                                                      \
        float g1 = dppf<0xB1>(h);   /* h[j^1] */           \
        float g2 = dppf<0x4E>(h);   /* h[j^2] */           \
        float g3 = dppf<0x1B>(h);   /* h[j^3] */           \
        float m7 = dppf<0x141>(h);  /* h[j^7] */           \
        float g4 = dppf<0x1B>(m7);  /* h[j^4] */           \
        float g5 = dppf<0x4E>(m7);  /* h[j^5] */           \
        float g6 = dppf<0xB1>(m7);  /* h[j^6] */           \
        float sa = fmaf((xval), wihC, bjC);                \
        sa = fmaf(wx[0], h,  sa);                          \
        float sb = wx[1] * g1;                             \
        float sc = wx[7] * m7;                             \
        sa = fmaf(wx[2], g2, sa);                          \
        sb = fmaf(wx[3], g3, sb);                          \
        sc = fmaf(wx[4], g4, sc);                          \
        sa = fmaf(wx[5], g5, sa);                          \
        sb = fmaf(wx[6], g6, sb);                          \
        float s = (sa + sb) + sc;  /* = C * preact */      \
        float e = __builtin_amdgcn_exp2f(s);               \
        h = 1.0f - 2.0f * __builtin_amdgcn_rcpf(1.0f + e); \
    }

    // Unroll 16 steps per iteration; prefetch the next 16 x-values one full
    // group ahead so the x stream never stalls the recurrence.
    float4 c0 = *(const float4*)(xp + 0);
    float4 c1 = *(const float4*)(xp + 4);
    float4 c2 = *(const float4*)(xp + 8);
    float4 c3 = *(const float4*)(xp + 12);

    for (int t = 0; t < T_STEPS; t += 16) {
        float4 n0 = c0, n1 = c1, n2 = c2, n3 = c3;
        if (t + 16 < T_STEPS) {
            n0 = *(const float4*)(xp + t + 16);
            n1 = *(const float4*)(xp + t + 20);
            n2 = *(const float4*)(xp + t + 24);
            n3 = *(const float4*)(xp + t + 28);
        }
        STEP(c0.x) STEP(c0.y) STEP(c0.z) STEP(c0.w)
        STEP(c1.x) STEP(c1.y) STEP(c1.z) STEP(c1.w)
        STEP(c2.x) STEP(c2.y) STEP(c2.z) STEP(c2.w)
        STEP(c3.x) STEP(c3.y) STEP(c3.z) STEP(c3.w)
        c0 = n0; c1 = n1; c2 = n2; c3 = n3;
    }
#undef STEP

    // Final FC (off the hot loop): gather h_T via __shfl; lane p==0 writes.
    float g[H];
#pragma unroll
    for (int k = 0; k < H; ++k) g[k] = __shfl(h, baseLane + k);
    if (p == 0) {
        float o = fc_b[0];
#pragma unroll
        for (int k = 0; k < H; ++k) o = fmaf(fc_w[k], g[k], o);
        out[chain] = o;
    }
}

extern "C" void kernel_launch(void* const* d_in, const int* in_sizes, int n_in,
                              void* d_out, int out_size, void* d_ws, size_t ws_size,
                              hipStream_t stream) {
    const float* x    = (const float*)d_in[0];
    const float* w_ih = (const float*)d_in[1];
    const float* w_hh = (const float*)d_in[2];
    const float* b_ih = (const float*)d_in[3];
    const float* b_hh = (const float*)d_in[4];
    const float* fc_w = (const float*)d_in[5];
    const float* fc_b = (const float*)d_in[6];
    float* out = (float*)d_out;

    dim3 grid(B_TOTAL / 16);   // 256 blocks -> 1 per CU
    dim3 block(256);           // 4 waves -> 1 per SIMD
    hipLaunchKernelGGL(rnn_fused, grid, block, 0, stream,
                       x, w_ih, w_hh, b_ih, b_hh, fc_w, fc_b, out);
}

// Round 3
// 162.936 us; speedup vs baseline: 1.7655x; 1.0789x over previous
//
#include <hip/hip_runtime.h>

// SmallRNN: B=4096 chains, T=2048 steps, I=1, H=8, O=1, fp32.
// h_t = tanh(x_t*w_ih + W_hh h_{t-1} + b);  out = fc_w . h_T + fc_b
//
// Round 3: exact-arithmetic critical-path cuts.
//  (a) r-state: iterate r = 1/(1+exp(2*pre)) instead of h = 1-2r.
//      Fold h = 1-2r into weights: W' = -2C*W, b' = C*(b + rowsum(W)).
//      Removes the tail fma from the loop-carried dependency.
//  (b) XOR4 at DPP depth 1: with the replica layout (lane p holds
//      r[(p&7)]), row_ror:4 (0x124) delivers r[j^4] in one hop —
//      rotation by +/-4 mod 8 is XOR4 either way, so ror direction
//      ambiguity is harmless. XOR5/XOR6 = half_mirror of g2/g1.
//  (c) x*wih + b' hoisted off the path (operands available at prefetch).
//
// Layout: 16 lanes per chain (8 hidden units x 2 replicas; replicas make
// the ror:4 trick work). 256 thr/block = 16 chains, grid 256 -> 1024
// waves = 1 wave/SIMD on all 256 CUs. Latency-bound by design.

#define B_TOTAL 4096
#define T_STEPS 2048
#define H 8

template <int CTRL>
__device__ __forceinline__ float dppf(float v) {
    int i = __float_as_int(v);
    i = __builtin_amdgcn_mov_dpp(i, CTRL, 0xF, 0xF, true);
    return __int_as_float(i);
}

__global__ __launch_bounds__(256, 1) void rnn_fused(
    const float* __restrict__ x,      // [4096, 2048]
    const float* __restrict__ w_ih,   // [8,1]
    const float* __restrict__ w_hh,   // [8,8]
    const float* __restrict__ b_ih,   // [8]
    const float* __restrict__ b_hh,   // [8]
    const float* __restrict__ fc_w,   // [1,8]
    const float* __restrict__ fc_b,   // [1]
    float* __restrict__ out)          // [4096,1]
{
    const int tid      = threadIdx.x;
    const int p        = tid & 15;          // position within 16-lane row
    const int j        = p & 7;             // hidden index (replica-agnostic)
    const int chain    = (blockIdx.x << 4) + (tid >> 4);
    const int baseLane = tid & 48;          // wave-relative base of this row

    // C = 2*log2(e): exp(2*pre) = exp2(C*pre).
    const float C = 2.885390081777927f;

    // r-state weights: pre*C = bP + sum_N wx[N]*r[j^N] + wihC*x
    //   wx[N] = -2*C*W[j][j^N],  bP = C*(b_j + sum_i W[j][i]),  wihC = C*wih_j
    float wx[H];
    float rowsum = 0.0f;
#pragma unroll
    for (int i = 0; i < H; ++i) rowsum += w_hh[j * H + i];
#pragma unroll
    for (int N = 0; N < H; ++N) wx[N] = -2.0f * C * w_hh[j * H + (j ^ N)];
    const float wihC = C * w_ih[j];
    const float bP   = C * (b_ih[j] + b_hh[j] + rowsum);

    const float* xp = x + (size_t)chain * T_STEPS;

    float r = 0.5f;   // h = 1 - 2r = 0

    // One RNN step. DPP levels: g1..g4,g7 depth-1 (ror:4 gives XOR4),
    // g5,g6 depth-2 consumed in the shortest chain. xwb is off-path.
#define STEP(xval)                                          \
    {                                                       \
        float xwb = fmaf((xval), wihC, bP);  /* off-path */ \
        float g1 = dppf<0xB1>(r);    /* r[j^1] */           \
        float g2 = dppf<0x4E>(r);    /* r[j^2] */           \
        float g3 = dppf<0x1B>(r);    /* r[j^3] */           \
        float g4 = dppf<0x124>(r);   /* r[j^4] row_ror:4 */ \
        float g7 = dppf<0x141>(r);   /* r[j^7] half_mir */  \
        float g5 = dppf<0x141>(g2);  /* r[j^5] */           \
        float g6 = dppf<0x141>(g1);  /* r[j^6] */           \
        float c1 = fmaf(wx[0], r, xwb);                     \
        c1 = fmaf(wx[1], g1, c1);                           \
        c1 = fmaf(wx[2], g2, c1);                           \
        float c2 = wx[3] * g3;                              \
        c2 = fmaf(wx[4], g4, c2);                           \
        float c3 = wx[7] * g7;                              \
        c3 = fmaf(wx[5], g5, c3);                           \
        c3 = fmaf(wx[6], g6, c3);                           \
        float s = (c1 + c2) + c3;                           \
        float e = __builtin_amdgcn_exp2f(s);                \
        r = __builtin_amdgcn_rcpf(1.0f + e);                \
    }

    // 16-step unroll; prefetch the next 16 x-values a full group ahead.
    float4 c0 = *(const float4*)(xp + 0);
    float4 c1v = *(const float4*)(xp + 4);
    float4 c2v = *(const float4*)(xp + 8);
    float4 c3v = *(const float4*)(xp + 12);

    for (int t = 0; t < T_STEPS; t += 16) {
        float4 n0 = c0, n1 = c1v, n2 = c2v, n3 = c3v;
        if (t + 16 < T_STEPS) {
            n0 = *(const float4*)(xp + t + 16);
            n1 = *(const float4*)(xp + t + 20);
            n2 = *(const float4*)(xp + t + 24);
            n3 = *(const float4*)(xp + t + 28);
        }
        STEP(c0.x) STEP(c0.y) STEP(c0.z) STEP(c0.w)
        STEP(c1v.x) STEP(c1v.y) STEP(c1v.z) STEP(c1v.w)
        STEP(c2v.x) STEP(c2v.y) STEP(c2v.z) STEP(c2v.w)
        STEP(c3v.x) STEP(c3v.y) STEP(c3v.z) STEP(c3v.w)
        c0 = n0; c1v = n1; c2v = n2; c3v = n3;
    }
#undef STEP

    // Final h from r-state; gather via __shfl (off hot loop); lane 0 writes.
    float h = fmaf(-2.0f, r, 1.0f);
    float g[H];
#pragma unroll
    for (int k = 0; k < H; ++k) g[k] = __shfl(h, baseLane + k);
    if (p == 0) {
        float o = fc_b[0];
#pragma unroll
        for (int k = 0; k < H; ++k) o = fmaf(fc_w[k], g[k], o);
        out[chain] = o;
    }
}

extern "C" void kernel_launch(void* const* d_in, const int* in_sizes, int n_in,
                              void* d_out, int out_size, void* d_ws, size_t ws_size,
                              hipStream_t stream) {
    const float* x    = (const float*)d_in[0];
    const float* w_ih = (const float*)d_in[1];
    const float* w_hh = (const float*)d_in[2];
    const float* b_ih = (const float*)d_in[3];
    const float* b_hh = (const float*)d_in[4];
    const float* fc_w = (const float*)d_in[5];
    const float* fc_b = (const float*)d_in[6];
    float* out = (float*)d_out;

    dim3 grid(B_TOTAL / 16);   // 256 blocks -> 1 per CU
    dim3 block(256);           // 4 waves -> 1 per SIMD
    hipLaunchKernelGGL(rnn_fused, grid, block, 0, stream,
                       x, w_ih, w_hh, b_ih, b_hh, fc_w, fc_b, out);
}